// Round 4
// baseline (355.895 us; speedup 1.0000x reference)
//
#include <hip/hip_runtime.h>
#include <math.h>

#define B_   8
#define N_   16384
#define M_   64
#define C_   192
#define RC_  16

typedef __attribute__((ext_vector_type(8))) _Float16 f16x8;
typedef __attribute__((ext_vector_type(4))) float    f32x4;
typedef unsigned int   u32;
typedef unsigned short u16;

#define LO_SCALE     2048.0f
#define LO_SCALE_INV (1.0f / 2048.0f)

// ---------------------------------------------------------------------------
// k_prep: per (b, c-slice of 32): v = dict@wv -> conv3x1 -> gelu -> fp16
// hi + scaled-lo split, stored TRANSPOSED as vgt_hi/vgt_lo [b][c][m]
// (B-fragment friendly: contiguous in m = the MFMA contraction axis).
// Slice 0 additionally computes k = l2norm(LN(dict@wk)) -> ws_k.
// grid = 48 blocks (8 b x 6 slices), 256 threads.
// ---------------------------------------------------------------------------
__global__ __launch_bounds__(256) void k_prep(
    const float* __restrict__ dict, const float* __restrict__ wv_w,
    const float* __restrict__ wv_b, const float* __restrict__ conv_w,
    const float* __restrict__ conv_b,
    const float* __restrict__ wk_w, const float* __restrict__ wk_b,
    const float* __restrict__ kn_g, const float* __restrict__ kn_b,
    _Float16* __restrict__ vgt_hi, _Float16* __restrict__ vgt_lo,
    float* __restrict__ ws_k)
{
    __shared__ float dict_s[M_ * C_];   // 48 KB
    __shared__ float vloc[M_ * 40];     // 10.2 KB (stride 40: 16B-aligned rows)

    const int t  = threadIdx.x;
    const int b  = blockIdx.x / 6;
    const int sl = blockIdx.x % 6;

    // stage dict[b] (12288 floats) coalesced
    {
        const float4* src = (const float4*)(dict + (size_t)b * M_ * C_);
        float4*       dst = (float4*)dict_s;
        #pragma unroll
        for (int i = 0; i < 12; ++i) dst[t + 256 * i] = src[t + 256 * i];
    }
    __syncthreads();

    const int m  = t >> 2;               // token row
    const int cg = (t & 3) * 8;          // 8 channels within 32-wide slice
    const int c0 = sl * 32 + cg;         // global channel base

    // ---- v[m][c0..c0+7] = dict_s[m,:] @ wv[:, c0..c0+7] + bias ----
    float acc[8];
    #pragma unroll
    for (int j = 0; j < 8; ++j) acc[j] = wv_b[c0 + j];
    #pragma unroll 4
    for (int d = 0; d < C_; ++d) {
        const float  xd = dict_s[m * C_ + d];
        const float4 wA = *(const float4*)&wv_w[d * C_ + c0];
        const float4 wB = *(const float4*)&wv_w[d * C_ + c0 + 4];
        acc[0] = fmaf(xd, wA.x, acc[0]); acc[1] = fmaf(xd, wA.y, acc[1]);
        acc[2] = fmaf(xd, wA.z, acc[2]); acc[3] = fmaf(xd, wA.w, acc[3]);
        acc[4] = fmaf(xd, wB.x, acc[4]); acc[5] = fmaf(xd, wB.y, acc[5]);
        acc[6] = fmaf(xd, wB.z, acc[6]); acc[7] = fmaf(xd, wB.w, acc[7]);
    }
    {
        float4 a0; a0.x = acc[0]; a0.y = acc[1]; a0.z = acc[2]; a0.w = acc[3];
        float4 a1; a1.x = acc[4]; a1.y = acc[5]; a1.z = acc[6]; a1.w = acc[7];
        *(float4*)&vloc[m * 40 + cg]     = a0;
        *(float4*)&vloc[m * 40 + cg + 4] = a1;
    }
    __syncthreads();

    // ---- conv along m (3x1 center column) + exact gelu + fp16 hi/lo ----
    #pragma unroll
    for (int j = 0; j < 8; ++j) {
        const int   c   = c0 + j;
        const float ctr = vloc[m * 40 + cg + j];
        const float up  = (m > 0)      ? vloc[(m - 1) * 40 + cg + j] : 0.0f;
        const float dn  = (m < M_ - 1) ? vloc[(m + 1) * 40 + cg + j] : 0.0f;
        const float w0 = conv_w[c * 9 + 1];
        const float w1 = conv_w[c * 9 + 4];
        const float w2 = conv_w[c * 9 + 7];
        float v = conv_b[c];
        v = fmaf(up, w0, v); v = fmaf(ctr, w1, v); v = fmaf(dn, w2, v);
        // exact GELU: 0.5*x*(1+erf(x/sqrt(2)))
        const float g = 0.5f * v * (1.0f + erff(v * 0.70710678118654752f));
        const _Float16 gh = (_Float16)g;
        const _Float16 gl = (_Float16)((g - (float)gh) * LO_SCALE);
        const size_t o = ((size_t)b * C_ + c) * M_ + m;
        vgt_hi[o] = gh;
        vgt_lo[o] = gl;
    }

    // ---- slice 0: k = l2norm(LN(dict@wk + b)) ----
    if (sl == 0) {
        const int j4  = t & 3;
        const int c0k = j4 * 4;
        const float* dr = dict_s + m * C_;
        float a0 = wk_b[c0k+0], a1 = wk_b[c0k+1], a2 = wk_b[c0k+2], a3 = wk_b[c0k+3];
        #pragma unroll 4
        for (int d4 = 0; d4 < C_/4; ++d4) {
            const float4 xv = *(const float4*)&dr[d4 * 4];
            const float4 w0 = *(const float4*)&wk_w[(d4*4+0)*RC_ + c0k];
            const float4 w1 = *(const float4*)&wk_w[(d4*4+1)*RC_ + c0k];
            const float4 w2 = *(const float4*)&wk_w[(d4*4+2)*RC_ + c0k];
            const float4 w3 = *(const float4*)&wk_w[(d4*4+3)*RC_ + c0k];
            a0 = fmaf(xv.x, w0.x, a0); a1 = fmaf(xv.x, w0.y, a1); a2 = fmaf(xv.x, w0.z, a2); a3 = fmaf(xv.x, w0.w, a3);
            a0 = fmaf(xv.y, w1.x, a0); a1 = fmaf(xv.y, w1.y, a1); a2 = fmaf(xv.y, w1.z, a2); a3 = fmaf(xv.y, w1.w, a3);
            a0 = fmaf(xv.z, w2.x, a0); a1 = fmaf(xv.z, w2.y, a1); a2 = fmaf(xv.z, w2.z, a2); a3 = fmaf(xv.z, w2.w, a3);
            a0 = fmaf(xv.w, w3.x, a0); a1 = fmaf(xv.w, w3.y, a1); a2 = fmaf(xv.w, w3.z, a2); a3 = fmaf(xv.w, w3.w, a3);
        }
        float s  = a0 + a1 + a2 + a3;
        float ss = a0*a0 + a1*a1 + a2*a2 + a3*a3;
        s  += __shfl_xor(s, 1);  s  += __shfl_xor(s, 2);
        ss += __shfl_xor(ss, 1); ss += __shfl_xor(ss, 2);
        const float mu   = s * (1.0f/16.0f);
        const float var  = ss * (1.0f/16.0f) - mu*mu;
        const float rstd = rsqrtf(var + 1e-5f);
        const float4 g4 = *(const float4*)&kn_g[c0k];
        const float4 b4 = *(const float4*)&kn_b[c0k];
        const float y0 = (a0 - mu) * rstd * g4.x + b4.x;
        const float y1 = (a1 - mu) * rstd * g4.y + b4.y;
        const float y2 = (a2 - mu) * rstd * g4.z + b4.z;
        const float y3 = (a3 - mu) * rstd * g4.w + b4.w;
        float n2 = y0*y0 + y1*y1 + y2*y2 + y3*y3;
        n2 += __shfl_xor(n2, 1); n2 += __shfl_xor(n2, 2);
        const float inv = 1.0f / fmaxf(sqrtf(n2), 1e-12f);
        float4 o; o.x = y0*inv; o.y = y1*inv; o.z = y2*inv; o.w = y3*inv;
        *(float4*)&ws_k[((size_t)b * M_ + m) * RC_ + c0k] = o;
    }
}

// ---------------------------------------------------------------------------
// k_main: 64 n-rows per block (wave w owns rows 16w..16w+15).
//   (a) q = l2norm(LN(x@wq+b))              fp32, shfl stats over 4 lanes/row
//   (b) attn = softmax(q.k/max(T,.5))       fp32 exact -> global; fp16 hi +
//       scaled-lo split -> LDS in A-fragment rows
//   (c) out = attn @ vg via mfma_f32_16x16x32_f16, two accumulators:
//       acc0 = Ah*Bh; acc1 = Ah*Bl + Al*Bh (lo pre-scaled by 2048);
//       out = acc0 + acc1/2048.  Residual ~2^-23 rel; even if acc1 were
//       zero, single-fp16 error ~9e-4 stays under threshold.
// ---------------------------------------------------------------------------
__global__ __launch_bounds__(256, 4) void k_main_kernel(
    const float* __restrict__ x, const float* __restrict__ ws_k,
    const _Float16* __restrict__ vgt_hi, const _Float16* __restrict__ vgt_lo,
    const float* __restrict__ wq_w, const float* __restrict__ wq_b,
    const float* __restrict__ qn_g, const float* __restrict__ qn_b,
    const float* __restrict__ temp,
    float* __restrict__ out, float* __restrict__ attn_out)
{
    __shared__ float q_s[M_ * 20];                                 // 5 KB
    __shared__ float k_s[M_ * RC_];                                // 4 KB
    __shared__ __attribute__((aligned(16))) _Float16 ahi_s[M_ * 72]; // 9.2 KB
    __shared__ __attribute__((aligned(16))) _Float16 alo_s[M_ * 72]; // 9.2 KB

    const int tid = threadIdx.x;
    const int b   = blockIdx.x >> 8;
    const int n0  = (blockIdx.x & 255) * M_;

    // stage k (1024 floats)
    ((float4*)k_s)[tid] = ((const float4*)(ws_k + (size_t)b * M_ * RC_))[tid];

    const int r  = tid >> 2;
    const int j4 = tid & 3;
    const int c0 = j4 * 4;

    // ---- phase (a): q projection + LN + l2norm ----
    const float* xr = x + (size_t)(b * N_ + n0 + r) * C_;
    float a0 = wq_b[c0+0], a1 = wq_b[c0+1], a2 = wq_b[c0+2], a3 = wq_b[c0+3];
    #pragma unroll 4
    for (int d4 = 0; d4 < C_/4; ++d4) {
        const float4 xv = ((const float4*)xr)[d4];
        // all 4 j4 slices of row d live in one 64B line -> broadcast-coalesced
        const float4 w0 = *(const float4*)&wq_w[(d4*4+0)*RC_ + c0];
        const float4 w1 = *(const float4*)&wq_w[(d4*4+1)*RC_ + c0];
        const float4 w2 = *(const float4*)&wq_w[(d4*4+2)*RC_ + c0];
        const float4 w3 = *(const float4*)&wq_w[(d4*4+3)*RC_ + c0];
        a0 = fmaf(xv.x, w0.x, a0); a1 = fmaf(xv.x, w0.y, a1); a2 = fmaf(xv.x, w0.z, a2); a3 = fmaf(xv.x, w0.w, a3);
        a0 = fmaf(xv.y, w1.x, a0); a1 = fmaf(xv.y, w1.y, a1); a2 = fmaf(xv.y, w1.z, a2); a3 = fmaf(xv.y, w1.w, a3);
        a0 = fmaf(xv.z, w2.x, a0); a1 = fmaf(xv.z, w2.y, a1); a2 = fmaf(xv.z, w2.z, a2); a3 = fmaf(xv.z, w2.w, a3);
        a0 = fmaf(xv.w, w3.x, a0); a1 = fmaf(xv.w, w3.y, a1); a2 = fmaf(xv.w, w3.z, a2); a3 = fmaf(xv.w, w3.w, a3);
    }
    {
        float s  = a0 + a1 + a2 + a3;
        float ss = a0*a0 + a1*a1 + a2*a2 + a3*a3;
        s  += __shfl_xor(s, 1);  s  += __shfl_xor(s, 2);
        ss += __shfl_xor(ss, 1); ss += __shfl_xor(ss, 2);
        const float mu   = s * (1.0f/16.0f);
        const float var  = ss * (1.0f/16.0f) - mu*mu;
        const float rstd = rsqrtf(var + 1e-5f);
        const float4 g4 = *(const float4*)&qn_g[c0];
        const float4 b4 = *(const float4*)&qn_b[c0];
        const float y0 = (a0 - mu) * rstd * g4.x + b4.x;
        const float y1 = (a1 - mu) * rstd * g4.y + b4.y;
        const float y2 = (a2 - mu) * rstd * g4.z + b4.z;
        const float y3 = (a3 - mu) * rstd * g4.w + b4.w;
        float n2 = y0*y0 + y1*y1 + y2*y2 + y3*y3;
        n2 += __shfl_xor(n2, 1); n2 += __shfl_xor(n2, 2);
        const float inv = 1.0f / fmaxf(sqrtf(n2), 1e-12f);
        float4 o; o.x = y0*inv; o.y = y1*inv; o.z = y2*inv; o.w = y3*inv;
        *(float4*)&q_s[r*20 + c0] = o;
    }

    __syncthreads();   // q_s, k_s visible

    // ---- phase (b): scores + softmax; attn -> global fp32 + LDS fp16 hi/lo ----
    {
        const float tinv = 1.0f / fmaxf(temp[0], 0.5f);
        const float4 q0 = *(const float4*)&q_s[r*20 + 0];
        const float4 q1 = *(const float4*)&q_s[r*20 + 4];
        const float4 q2 = *(const float4*)&q_s[r*20 + 8];
        const float4 q3 = *(const float4*)&q_s[r*20 + 12];
        float sc[16];
        #pragma unroll
        for (int mm = 0; mm < 16; ++mm) {
            const int m = j4*16 + mm;
            const float4 k0 = *(const float4*)&k_s[m*RC_ + 0];
            const float4 k1 = *(const float4*)&k_s[m*RC_ + 4];
            const float4 k2 = *(const float4*)&k_s[m*RC_ + 8];
            const float4 k3 = *(const float4*)&k_s[m*RC_ + 12];
            float d = q0.x*k0.x;
            d = fmaf(q0.y, k0.y, d); d = fmaf(q0.z, k0.z, d); d = fmaf(q0.w, k0.w, d);
            d = fmaf(q1.x, k1.x, d); d = fmaf(q1.y, k1.y, d); d = fmaf(q1.z, k1.z, d); d = fmaf(q1.w, k1.w, d);
            d = fmaf(q2.x, k2.x, d); d = fmaf(q2.y, k2.y, d); d = fmaf(q2.z, k2.z, d); d = fmaf(q2.w, k2.w, d);
            d = fmaf(q3.x, k3.x, d); d = fmaf(q3.y, k3.y, d); d = fmaf(q3.w, k3.w, d); d = fmaf(q3.z, k3.z, d);
            sc[mm] = d * tinv;
        }
        float mx = sc[0];
        #pragma unroll
        for (int mm = 1; mm < 16; ++mm) mx = fmaxf(mx, sc[mm]);
        mx = fmaxf(mx, __shfl_xor(mx, 1)); mx = fmaxf(mx, __shfl_xor(mx, 2));
        float es = 0.0f;
        #pragma unroll
        for (int mm = 0; mm < 16; ++mm) { sc[mm] = expf(sc[mm] - mx); es += sc[mm]; }
        es += __shfl_xor(es, 1); es += __shfl_xor(es, 2);
        const float einv = 1.0f / es;
        #pragma unroll
        for (int mm = 0; mm < 16; ++mm) sc[mm] *= einv;

        // exact fp32 attn to global, coalesced float4
        float* aw = attn_out + (size_t)(b * N_ + n0 + r) * M_ + j4*16;
        #pragma unroll
        for (int mq = 0; mq < 4; ++mq) {
            float4 av;
            av.x = sc[mq*4+0]; av.y = sc[mq*4+1]; av.z = sc[mq*4+2]; av.w = sc[mq*4+3];
            ((float4*)aw)[mq] = av;
        }
        // fp16 hi + scaled-lo split -> LDS rows (A-fragment source)
        f16x8 h0v, h1v, l0v, l1v;
        #pragma unroll
        for (int i = 0; i < 8; ++i) {
            const _Float16 ha = (_Float16)sc[i];
            h0v[i] = ha;
            l0v[i] = (_Float16)((sc[i] - (float)ha) * LO_SCALE);
            const _Float16 hb = (_Float16)sc[i + 8];
            h1v[i] = hb;
            l1v[i] = (_Float16)((sc[i + 8] - (float)hb) * LO_SCALE);
        }
        *(f16x8*)&ahi_s[r*72 + j4*16]     = h0v;
        *(f16x8*)&ahi_s[r*72 + j4*16 + 8] = h1v;
        *(f16x8*)&alo_s[r*72 + j4*16]     = l0v;
        *(f16x8*)&alo_s[r*72 + j4*16 + 8] = l1v;
    }

    __syncthreads();   // ahi_s/alo_s visible

    // ---- phase (c): out = attn @ vg via f16 MFMA, compensated ----
    {
        const int w    = tid >> 6;          // wave -> owns rows 16w..16w+15
        const int lane = tid & 63;
        const int n16  = lane & 15;         // A: row idx / B,D: col idx
        const int g    = lane >> 4;         // quad
        const int gr   = w * 16 + n16;

        // A-fragments: A[row=gr][k = 32s + 8g + j]
        const f16x8 Ah0 = *(const f16x8*)&ahi_s[gr*72 +      8*g];
        const f16x8 Ah1 = *(const f16x8*)&ahi_s[gr*72 + 32 + 8*g];
        const f16x8 Al0 = *(const f16x8*)&alo_s[gr*72 +      8*g];
        const f16x8 Al1 = *(const f16x8*)&alo_s[gr*72 + 32 + 8*g];

        // B-fragments from global: B[k = 32s+8g+j][n] at vgt[b][nt*16+n16][k]
        const _Float16* bh = vgt_hi + ((size_t)b * C_ + n16) * M_ + 8*g;
        const _Float16* bl = vgt_lo + ((size_t)b * C_ + n16) * M_ + 8*g;

        float* obase = out + (size_t)(b * N_ + n0 + w*16 + 4*g) * C_ + n16;

        #pragma unroll
        for (int nt = 0; nt < 12; ++nt) {
            const int off = nt * 16 * M_;
            const f16x8 Bh0 = *(const f16x8*)(bh + off);
            const f16x8 Bl0 = *(const f16x8*)(bl + off);
            const f16x8 Bh1 = *(const f16x8*)(bh + off + 32);
            const f16x8 Bl1 = *(const f16x8*)(bl + off + 32);
            f32x4 acc0 = (f32x4)(0.0f);
            f32x4 acc1 = (f32x4)(0.0f);
            acc0 = __builtin_amdgcn_mfma_f32_16x16x32_f16(Ah0, Bh0, acc0, 0, 0, 0);
            acc0 = __builtin_amdgcn_mfma_f32_16x16x32_f16(Ah1, Bh1, acc0, 0, 0, 0);
            acc1 = __builtin_amdgcn_mfma_f32_16x16x32_f16(Ah0, Bl0, acc1, 0, 0, 0);
            acc1 = __builtin_amdgcn_mfma_f32_16x16x32_f16(Al0, Bh0, acc1, 0, 0, 0);
            acc1 = __builtin_amdgcn_mfma_f32_16x16x32_f16(Ah1, Bl1, acc1, 0, 0, 0);
            acc1 = __builtin_amdgcn_mfma_f32_16x16x32_f16(Al1, Bh1, acc1, 0, 0, 0);
            // D: col = lane&15, row = 4g + reg
            #pragma unroll
            for (int rg = 0; rg < 4; ++rg)
                obase[(size_t)rg * C_ + nt*16] = acc0[rg] + acc1[rg] * LO_SCALE_INV;
        }
    }
}

// ---------------------------------------------------------------------------
extern "C" void kernel_launch(void* const* d_in, const int* in_sizes, int n_in,
                              void* d_out, int out_size, void* d_ws, size_t ws_size,
                              hipStream_t stream) {
    const float* x      = (const float*)d_in[0];
    const float* dict   = (const float*)d_in[1];
    // d_in[2]=H, d_in[3]=W (unused: M-axis conv only)
    const float* wq_w   = (const float*)d_in[4];
    const float* wq_b   = (const float*)d_in[5];
    const float* wk_w   = (const float*)d_in[6];
    const float* wk_b   = (const float*)d_in[7];
    const float* wv_w   = (const float*)d_in[8];
    const float* wv_b   = (const float*)d_in[9];
    const float* qn_g   = (const float*)d_in[10];
    const float* qn_b   = (const float*)d_in[11];
    const float* kn_g   = (const float*)d_in[12];
    const float* kn_b   = (const float*)d_in[13];
    const float* conv_w = (const float*)d_in[14];
    const float* conv_b = (const float*)d_in[15];
    const float* temp   = (const float*)d_in[16];

    float* out  = (float*)d_out;                          // (B,N,192)
    float* attn = out + (size_t)B_ * N_ * C_;             // (B,N,64)

    float*    ws_k   = (float*)d_ws;                          // 8192 f = 32 KB
    _Float16* vgt_hi = (_Float16*)(ws_k + (size_t)B_ * M_ * RC_); // 98304 h = 192 KB
    _Float16* vgt_lo = vgt_hi + (size_t)B_ * C_ * M_;             // 192 KB

    k_prep<<<B_ * 6, 256, 0, stream>>>(dict, wv_w, wv_b, conv_w, conv_b,
                                       wk_w, wk_b, kn_g, kn_b,
                                       vgt_hi, vgt_lo, ws_k);
    k_main_kernel<<<B_ * (N_ / M_), 256, 0, stream>>>(x, ws_k, vgt_hi, vgt_lo,
                                                      wq_w, wq_b, qn_g, qn_b,
                                                      temp, out, attn);
}